// Round 1
// baseline (34.768 us; speedup 1.0000x reference)
//
#include <hip/hip_runtime.h>

#define NPTS 2048
#define NBATCH 8
#define COUT 9
#define QCELLS 16
#define WAVES_PER_BLOCK 4

__global__ __launch_bounds__(256) void pconv_wave_per_center(
    const float* __restrict__ pts,    // [B, N, 3]
    const float* __restrict__ attrs,  // [B, N, 1]
    const float* __restrict__ cw,     // [COUT, 1, 16] flat
    const float* __restrict__ cb,     // [COUT]
    float* __restrict__ out)          // [B, N, COUT]
{
    const int lane = threadIdx.x & 63;
    const int w    = threadIdx.x >> 6;                 // wave index in block
    const int wid  = blockIdx.x * WAVES_PER_BLOCK + w; // global center id
    if (wid >= NBATCH * NPTS) return;
    const int b = wid >> 11;    // / NPTS
    const int i = wid & (NPTS - 1);

    __shared__ unsigned long long s_sum[WAVES_PER_BLOCK][QCELLS]; // fixed-point Q32.32
    __shared__ unsigned int       s_cnt[WAVES_PER_BLOCK][QCELLS];
    __shared__ float              s_mean[WAVES_PER_BLOCK][QCELLS];

    if (lane < QCELLS) {
        s_sum[w][lane] = 0ull;
        s_cnt[w][lane] = 0u;
    }
    // wave-private bins; LDS ops within a wave are in program order — no barrier needed here.

    const float* pb = pts   + (size_t)b * NPTS * 3;
    const float* ab = attrs + (size_t)b * NPTS;

    const float cx = pb[i * 3 + 0];
    const float cy = pb[i * 3 + 1];
    const float cz = pb[i * 3 + 2];

    #pragma unroll 4
    for (int j = lane; j < NPTS; j += 64) {
        const float px = pb[j * 3 + 0];
        const float py = pb[j * 3 + 1];
        const float pz = pb[j * 3 + 2];
        const float a  = ab[j];

        // d = p_center - p_neighbor  (matches reference d[i][j] = points[i] - points[j])
        const float dx = __fsub_rn(cx, px);
        const float dy = __fsub_rn(cy, py);
        const float dz = __fsub_rn(cz, pz);
        // strict IEEE mul/add (no fma contraction) to match numpy: (x*x + y*y) + z*z
        const float d2 = __fadd_rn(__fadd_rn(__fmul_rn(dx, dx), __fmul_rn(dy, dy)),
                                   __fmul_rn(dz, dz));
        const float dist = sqrtf(d2);   // correctly-rounded (no fast-math)

        if (dist <= 0.1f) {             // rare: ~0.4% of pairs
            const int oct = (dx >= 0.0f ? 1 : 0)
                          + (dy >= 0.0f ? 2 : 0)
                          + (dz >= 0.0f ? 4 : 0);
            // shell = min((int)(dist / 0.05f), 1) — true IEEE division, as reference
            const float t = dist / 0.05f;
            const int shell = ((int)t) >= 1 ? 1 : 0;
            const int cell = shell * 8 + oct;

            // deterministic fixed-point accumulation (integer adds commute exactly)
            const long long av = (long long)llrintf(a * 4294967296.0f); // *2^32 exact scale
            atomicAdd(&s_sum[w][cell], (unsigned long long)av);
            atomicAdd(&s_cnt[w][cell], 1u);
        }
    }

    __syncthreads();

    if (lane < QCELLS) {
        const long long s = (long long)s_sum[w][lane];
        const unsigned  c = s_cnt[w][lane];
        const float sum  = (float)((double)s * (1.0 / 4294967296.0));
        const float mean = sum / (float)(c > 0u ? c : 1u);
        s_mean[w][lane] = mean;
    }
    // s_mean written and read by the same wave; ds ops are in program order per wave.

    if (lane < COUT) {
        float acc = cb[lane];
        #pragma unroll
        for (int q = 0; q < QCELLS; ++q)
            acc = fmaf(s_mean[w][q], cw[lane * QCELLS + q], acc);
        out[((size_t)b * NPTS + i) * COUT + lane] = acc;
    }
}

extern "C" void kernel_launch(void* const* d_in, const int* in_sizes, int n_in,
                              void* d_out, int out_size, void* d_ws, size_t ws_size,
                              hipStream_t stream) {
    const float* pts   = (const float*)d_in[0]; // [8,2048,3]
    const float* attrs = (const float*)d_in[1]; // [8,2048,1]
    const float* cw    = (const float*)d_in[2]; // [9,1,16]
    const float* cb    = (const float*)d_in[3]; // [9]
    float* out = (float*)d_out;                 // [8,2048,9]

    const int n_centers = NBATCH * NPTS;
    const int n_blocks  = n_centers / WAVES_PER_BLOCK; // 4096
    pconv_wave_per_center<<<n_blocks, 256, 0, stream>>>(pts, attrs, cw, cb, out);
}

// Round 2
// 30.385 us; speedup vs baseline: 1.1443x; 1.1443x over previous
//
#include <hip/hip_runtime.h>

#define NPTS 2048
#define NBATCH 8
#define NC (NBATCH * NPTS)
#define COUT 9
#define QCELLS 16
#define WPB 4   // waves per block
#define CPW 4   // centers per wave

// ---- prologue: pack (x,y,z,attr) into float4 so hot loop is 1 dwordx4/pair ----
__global__ __launch_bounds__(256) void pack_kernel(const float* __restrict__ pts,
                                                   const float* __restrict__ attrs,
                                                   float4* __restrict__ packed) {
    const int idx = blockIdx.x * 256 + threadIdx.x;
    if (idx < NC) {
        packed[idx] = make_float4(pts[idx * 3 + 0], pts[idx * 3 + 1],
                                  pts[idx * 3 + 2], attrs[idx]);
    }
}

// ---- main: wave-per-4-centers, lanes sweep j ----
template <bool PACKED>
__global__ __launch_bounds__(256) void pconv_main(
    const float4* __restrict__ packed,
    const float* __restrict__ pts,
    const float* __restrict__ attrs,
    const float* __restrict__ cw,   // [COUT,1,16] flat
    const float* __restrict__ cb,   // [COUT]
    float* __restrict__ out)        // [B,N,COUT]
{
    const int lane = threadIdx.x & 63;
    const int w    = threadIdx.x >> 6;
    const int wid  = blockIdx.x * WPB + w;
    const int ci0  = wid * CPW;          // first of 4 consecutive centers (same batch: 2048%4==0)
    const int b    = ci0 >> 11;
    const int i0   = ci0 & (NPTS - 1);

    __shared__ unsigned long long s_sum[WPB][CPW][QCELLS];  // fixed-point Q32.32
    __shared__ unsigned int       s_cnt[WPB][CPW][QCELLS];
    __shared__ float              s_mean[WPB][CPW][QCELLS];

    // one bin per lane: 4 centers x 16 cells = 64
    s_sum[w][lane >> 4][lane & 15] = 0ull;
    s_cnt[w][lane >> 4][lane & 15] = 0u;

    const float4* pb4 = packed + (size_t)b * NPTS;
    const float*  pbs = pts    + (size_t)b * NPTS * 3;
    const float*  abs_ = attrs + (size_t)b * NPTS;

    float cx[CPW], cy[CPW], cz[CPW];
    #pragma unroll
    for (int c = 0; c < CPW; ++c) {
        if constexpr (PACKED) {
            const float4 p = pb4[i0 + c];
            cx[c] = p.x; cy[c] = p.y; cz[c] = p.z;
        } else {
            cx[c] = pbs[(i0 + c) * 3 + 0];
            cy[c] = pbs[(i0 + c) * 3 + 1];
            cz[c] = pbs[(i0 + c) * 3 + 2];
        }
    }

    #pragma unroll 4
    for (int j = lane; j < NPTS; j += 64) {
        float4 p;
        if constexpr (PACKED) {
            p = pb4[j];
        } else {
            p.x = pbs[j * 3 + 0]; p.y = pbs[j * 3 + 1]; p.z = pbs[j * 3 + 2];
            p.w = abs_[j];
        }
        #pragma unroll
        for (int c = 0; c < CPW; ++c) {
            // strict IEEE, no contraction, matches numpy: (x*x + y*y) + z*z
            const float dx = __fsub_rn(cx[c], p.x);
            const float dy = __fsub_rn(cy[c], p.y);
            const float dz = __fsub_rn(cz[c], p.z);
            const float d2 = __fadd_rn(__fadd_rn(__fmul_rn(dx, dx), __fmul_rn(dy, dy)),
                                       __fmul_rn(dz, dz));
            // conservative prefilter: every d2 with sqrtf(d2)<=0.1f has d2<=0.0100000019
            if (d2 <= 0.0100001f) {
                const float dist = sqrtf(d2);           // IEEE, exact semantics
                if (dist <= 0.1f) {
                    const int oct = (dx >= 0.0f ? 1 : 0)
                                  + (dy >= 0.0f ? 2 : 0)
                                  + (dz >= 0.0f ? 4 : 0);
                    // int(dist/0.05f) >= 1  <=>  dist >= 0.05f  (exact; 0.1f==2*0.05f)
                    const int cell = (dist >= 0.05f ? 8 : 0) + oct;
                    const long long av = (long long)llrintf(p.w * 4294967296.0f);
                    atomicAdd(&s_sum[w][c][cell], (unsigned long long)av);
                    atomicAdd(&s_cnt[w][c][cell], 1u);
                }
            }
        }
    }

    __syncthreads();

    {   // per-cell means: 64 bins == 64 lanes
        const int c = lane >> 4, q = lane & 15;
        const long long      s = (long long)s_sum[w][c][q];
        const unsigned int cnt = s_cnt[w][c][q];
        const float sum = (float)((double)s * (1.0 / 4294967296.0));
        s_mean[w][c][q] = sum / (float)(cnt ? cnt : 1u);
    }

    __syncthreads();

    if (lane < CPW * COUT) {   // 36 active lanes
        const int c = lane / COUT;
        const int o = lane - c * COUT;
        float acc = cb[o];
        #pragma unroll
        for (int q = 0; q < QCELLS; ++q)
            acc = fmaf(s_mean[w][c][q], cw[o * QCELLS + q], acc);
        out[(size_t)(ci0 + c) * COUT + o] = acc;
    }
}

extern "C" void kernel_launch(void* const* d_in, const int* in_sizes, int n_in,
                              void* d_out, int out_size, void* d_ws, size_t ws_size,
                              hipStream_t stream) {
    const float* pts   = (const float*)d_in[0];  // [8,2048,3]
    const float* attrs = (const float*)d_in[1];  // [8,2048,1]
    const float* cw    = (const float*)d_in[2];  // [9,1,16]
    const float* cb    = (const float*)d_in[3];  // [9]
    float* out = (float*)d_out;                  // [8,2048,9]

    const int n_blocks = NC / (WPB * CPW);       // 1024

    if (ws_size >= (size_t)NC * sizeof(float4)) {
        float4* packed = (float4*)d_ws;
        pack_kernel<<<(NC + 255) / 256, 256, 0, stream>>>(pts, attrs, packed);
        pconv_main<true><<<n_blocks, 256, 0, stream>>>(packed, pts, attrs, cw, cb, out);
    } else {
        pconv_main<false><<<n_blocks, 256, 0, stream>>>(nullptr, pts, attrs, cw, cb, out);
    }
}

// Round 3
// 22.673 us; speedup vs baseline: 1.5335x; 1.3402x over previous
//
#include <hip/hip_runtime.h>
#include <math.h>

#define NPTS 2048
#define NBATCH 8
#define NC (NBATCH * NPTS)
#define COUT 9
#define QCELLS 16
#define WPB 4   // waves per block
#define CPW 2   // centers per wave
#define SCALE 65536.0f

// ---- prologue: pack (x,y,z,attr) into float4 so hot loop is 1 dwordx4/pair ----
__global__ __launch_bounds__(256) void pack_kernel(const float* __restrict__ pts,
                                                   const float* __restrict__ attrs,
                                                   float4* __restrict__ packed) {
    const int idx = blockIdx.x * 256 + threadIdx.x;
    if (idx < NC) {
        packed[idx] = make_float4(pts[idx * 3 + 0], pts[idx * 3 + 1],
                                  pts[idx * 3 + 2], attrs[idx]);
    }
}

__global__ __launch_bounds__(256) void pconv_main(
    const float4* __restrict__ packed,
    const float* __restrict__ cw,   // [COUT,1,16] flat
    const float* __restrict__ cb,   // [COUT]
    float* __restrict__ out)        // [B,N,COUT]
{
    const int lane = threadIdx.x & 63;
    const int w    = threadIdx.x >> 6;
    const int wid  = blockIdx.x * WPB + w;
    const int ci0  = wid * CPW;               // 2 consecutive centers, same batch (2048%2==0)
    const int b    = ci0 >> 11;
    const int i0   = ci0 & (NPTS - 1);

    __shared__ int          s_sum[WPB][CPW][QCELLS];   // fixed-point Q16
    __shared__ unsigned int s_cnt[WPB][CPW][QCELLS];
    __shared__ float        s_mean[WPB][CPW][QCELLS];

    if (lane < CPW * QCELLS) {
        s_sum[w][lane >> 4][lane & 15] = 0;
        s_cnt[w][lane >> 4][lane & 15] = 0u;
    }

    // Exact float thresholds reproducing reference semantics:
    //   valid:  sqrt_rn(d2) <= 0.1f          <=>  (real) d2 < midR^2   <=> d2 <= T1
    //   shell1: trunc(dist/0.05f) >= 1       <=>  dist >= 0.05f
    //           <=> (real) d2 > mid2^2       <=> d2 >= T2
    // midR  = (0.1f + nextafter(0.1f))/2 = 26843547 * 2^-28   (exact in double)
    // mid2  = (prev(0.05f) + 0.05f)/2   = 26843545 * 2^-29    (exact in double)
    // squares of 25-bit ints are <= 50 bits => exact in double; a 24-bit float
    // can never equal these odd-mantissa boundaries, so no tie cases exist.
    constexpr double MIDR   = 26843547.0 / 268435456.0;
    constexpr double MIDR2  = MIDR * MIDR;
    constexpr double MID2   = 26843545.0 / 536870912.0;
    constexpr double MID2SQ = MID2 * MID2;
    float T1 = (float)MIDR2;  if ((double)T1 >= MIDR2)  T1 = nextafterf(T1, 0.0f);
    float T2 = (float)MID2SQ; if ((double)T2 <= MID2SQ) T2 = nextafterf(T2, 1.0f);

    const float4* pb4 = packed + (size_t)b * NPTS;

    const float4 c0 = pb4[i0];
    const float4 c1 = pb4[i0 + 1];
    const float cx0 = c0.x, cy0 = c0.y, cz0 = c0.z;
    const float cx1 = c1.x, cy1 = c1.y, cz1 = c1.z;

    float4 p = pb4[lane];
    for (int j0 = 0; j0 < NPTS; j0 += 64) {
        const int jn = (j0 + 64) & (NPTS - 1);      // wraps on last iter (dummy reload)
        const float4 pn = pb4[jn + lane];           // prefetch: independent of branches below

        const int av = __float2int_rn(p.w * SCALE); // fixed-point attr, once per j

        // strict IEEE mul/add, matches numpy (x*x + y*y) + z*z
        const float dx0 = __fsub_rn(cx0, p.x);
        const float dy0 = __fsub_rn(cy0, p.y);
        const float dz0 = __fsub_rn(cz0, p.z);
        const float d20 = __fadd_rn(__fadd_rn(__fmul_rn(dx0, dx0), __fmul_rn(dy0, dy0)),
                                    __fmul_rn(dz0, dz0));
        const float dx1 = __fsub_rn(cx1, p.x);
        const float dy1 = __fsub_rn(cy1, p.y);
        const float dz1 = __fsub_rn(cz1, p.z);
        const float d21 = __fadd_rn(__fadd_rn(__fmul_rn(dx1, dx1), __fmul_rn(dy1, dy1)),
                                    __fmul_rn(dz1, dz1));

        const bool v0 = (d20 <= T1);
        const bool v1 = (d21 <= T1);
        if (v0 || v1) {                              // one exec-mask region for both centers
            if (v0) {
                const int oct = (dx0 >= 0.0f ? 1 : 0) + (dy0 >= 0.0f ? 2 : 0)
                              + (dz0 >= 0.0f ? 4 : 0);
                const int cell = (d20 >= T2 ? 8 : 0) + oct;
                atomicAdd(&s_sum[w][0][cell], av);
                atomicAdd(&s_cnt[w][0][cell], 1u);
            }
            if (v1) {
                const int oct = (dx1 >= 0.0f ? 1 : 0) + (dy1 >= 0.0f ? 2 : 0)
                              + (dz1 >= 0.0f ? 4 : 0);
                const int cell = (d21 >= T2 ? 8 : 0) + oct;
                atomicAdd(&s_sum[w][1][cell], av);
                atomicAdd(&s_cnt[w][1][cell], 1u);
            }
        }
        p = pn;
    }

    __syncthreads();

    if (lane < CPW * QCELLS) {                       // 32 bins per wave
        const int c = lane >> 4, q = lane & 15;
        const int          s = s_sum[w][c][q];
        const unsigned int n = s_cnt[w][c][q];
        s_mean[w][c][q] = ((float)s * (1.0f / SCALE)) / (float)(n ? n : 1u);
    }

    __syncthreads();

    if (lane < CPW * COUT) {                         // 18 active lanes
        const int c = (lane >= COUT) ? 1 : 0;
        const int o = lane - c * COUT;
        float acc = cb[o];
        #pragma unroll
        for (int q = 0; q < QCELLS; ++q)
            acc = fmaf(s_mean[w][c][q], cw[o * QCELLS + q], acc);
        out[(size_t)(ci0 + c) * COUT + o] = acc;
    }
}

extern "C" void kernel_launch(void* const* d_in, const int* in_sizes, int n_in,
                              void* d_out, int out_size, void* d_ws, size_t ws_size,
                              hipStream_t stream) {
    const float* pts   = (const float*)d_in[0];  // [8,2048,3]
    const float* attrs = (const float*)d_in[1];  // [8,2048,1]
    const float* cw    = (const float*)d_in[2];  // [9,1,16]
    const float* cb    = (const float*)d_in[3];  // [9]
    float* out = (float*)d_out;                  // [8,2048,9]

    float4* packed = (float4*)d_ws;              // ws is plenty (>= NC*16 bytes)
    pack_kernel<<<(NC + 255) / 256, 256, 0, stream>>>(pts, attrs, packed);

    const int n_blocks = NC / (WPB * CPW);       // 2048 -> 8 blocks/CU, 8 waves/SIMD
    pconv_main<<<n_blocks, 256, 0, stream>>>(packed, cw, cb, out);
}